// Round 7
// baseline (172.771 us; speedup 1.0000x reference)
//
#include <hip/hip_runtime.h>

typedef unsigned short u16;
typedef unsigned int u32;
typedef __bf16 bf16x8 __attribute__((ext_vector_type(8)));
typedef float f32x16 __attribute__((ext_vector_type(16)));
typedef int i32x4 __attribute__((ext_vector_type(4)));
typedef u32 u32x2 __attribute__((ext_vector_type(2)));

#define T_ 5000
#define CAP 96  // bucket capacity; ovf path guarantees correctness on overflow

__device__ __forceinline__ u16 f2bf(float f) {
  u32 u = __float_as_uint(f);
  u += 0x7fffu + ((u >> 16) & 1u);
  return (u16)(u >> 16);
}

__device__ __forceinline__ void gload_lds16(const u16* g, u16* l) {
  __builtin_amdgcn_global_load_lds(
      (__attribute__((address_space(1))) void*)(u16*)g,
      (__attribute__((address_space(3))) void*)l, 16, 0, 0);
}

__device__ __forceinline__ u32 lds_off(const void* p) {
  return (u32)(uintptr_t)(__attribute__((address_space(3))) const void*)p;
}

// LDS tile swizzle (involution): tile byte (row, kb in [0,64)) ->
//   (row>>1)*128 + ((((row&1)<<6)|kb) ^ (((row>>1)&7)<<4))
__device__ __forceinline__ u32 swz(int row, int kb) {
  return (u32)((row >> 1) * 128 +
               ((((row & 1) << 6) | kb) ^ (((row >> 1) & 7) << 4)));
}

// Ws transpose (f32 [2][512][512] -> bf16 transposed) + zero bucket counters
__global__ void prep_k(const float* __restrict__ src, u16* __restrict__ dst,
                       int* __restrict__ cnt) {
  __shared__ float tile[32][33];
  const int tx = threadIdx.x, ty = threadIdx.y;
  const int a0 = blockIdx.x * 32;
  const int b0 = blockIdx.y * 32;
  const size_t zoff = (size_t)blockIdx.z * (512 * 512);
  const float* s = src + zoff;
  u16* d = dst + zoff;
#pragma unroll
  for (int r = 0; r < 4; ++r)
    tile[ty + r * 8][tx] = s[(size_t)(a0 + ty + r * 8) * 512 + b0 + tx];
  const int gid = ((blockIdx.z * 16 + blockIdx.y) * 16 + blockIdx.x) * 256 + ty * 32 + tx;
  if (gid < 5008) cnt[gid] = 0;
  __syncthreads();
#pragma unroll
  for (int r = 0; r < 4; ++r)
    d[(size_t)(b0 + ty + r * 8) * 512 + a0 + tx] = f2bf(tile[tx][ty + r * 8]);
}

// cd[t] = {col, bits(diag)}; bucket instance t into list[row]
__global__ void fill_k(const int* __restrict__ ev, const float* __restrict__ ui,
                       int2* __restrict__ cd, int* __restrict__ cnt,
                       int* __restrict__ list, int* __restrict__ ovf) {
  const int t = blockIdx.x * 256 + threadIdx.x;  // 0..32767
  const int r = ev[t] - 1;
  int2 v;
  v.x = r;
  v.y = __float_as_int(ui[(size_t)r * (T_ + 1)]);
  cd[t] = v;
  const int pos = atomicAdd(&cnt[r], 1);
  if (pos < CAP) list[r * CAP + pos] = t;
  else { const int o = atomicAdd(&cnt[5000], 1); ovf[o] = t; }
}

// one block per distinct ui row: stage row + instance list in LDS, serve 4-way.
__global__ __launch_bounds__(256)
void grow_gather(const float* __restrict__ ui, const int2* __restrict__ cd,
                 const int* __restrict__ cnt, const int* __restrict__ list,
                 const int* __restrict__ ovf, u16* __restrict__ adj) {
  __shared__ float row[5000];
  __shared__ int lst[CAP];
  const int r = blockIdx.x;
  int c = cnt[r];
  if (c > CAP) c = CAP;
  const int j = threadIdx.x * 2;
  if (c > 0) {
    const float* __restrict__ src = ui + (size_t)r * T_;
    for (int t = threadIdx.x; t < 1250; t += 256)
      *(float4*)&row[t * 4] = *(const float4*)&src[t * 4];
    if (threadIdx.x < c) lst[threadIdx.x] = list[r * CAP + threadIdx.x];
    __syncthreads();
    int q = 0;
    for (; q + 4 <= c; q += 4) {
      const int t0 = lst[q], t1 = lst[q + 1], t2 = lst[q + 2], t3 = lst[q + 3];
      const int4 p0 = *(const int4*)&cd[((t0 >> 9) << 9) + j];
      const int4 p1 = *(const int4*)&cd[((t1 >> 9) << 9) + j];
      const int4 p2 = *(const int4*)&cd[((t2 >> 9) << 9) + j];
      const int4 p3 = *(const int4*)&cd[((t3 >> 9) << 9) + j];
      const u32 k0 = (u32)f2bf(row[p0.x] + __int_as_float(p0.y)) |
                     ((u32)f2bf(row[p0.z] + __int_as_float(p0.w)) << 16);
      const u32 k1 = (u32)f2bf(row[p1.x] + __int_as_float(p1.y)) |
                     ((u32)f2bf(row[p1.z] + __int_as_float(p1.w)) << 16);
      const u32 k2 = (u32)f2bf(row[p2.x] + __int_as_float(p2.y)) |
                     ((u32)f2bf(row[p2.z] + __int_as_float(p2.w)) << 16);
      const u32 k3 = (u32)f2bf(row[p3.x] + __int_as_float(p3.y)) |
                     ((u32)f2bf(row[p3.z] + __int_as_float(p3.w)) << 16);
      *(u32*)&adj[(size_t)t0 * 512 + j] = k0;
      *(u32*)&adj[(size_t)t1 * 512 + j] = k1;
      *(u32*)&adj[(size_t)t2 * 512 + j] = k2;
      *(u32*)&adj[(size_t)t3 * 512 + j] = k3;
    }
    for (; q < c; ++q) {
      const int t0 = lst[q];
      const int4 p0 = *(const int4*)&cd[((t0 >> 9) << 9) + j];
      const u32 k0 = (u32)f2bf(row[p0.x] + __int_as_float(p0.y)) |
                     ((u32)f2bf(row[p0.z] + __int_as_float(p0.w)) << 16);
      *(u32*)&adj[(size_t)t0 * 512 + j] = k0;
    }
  }
  if (r < 8) {
    const int n = cnt[5000];
    for (int q = r; q < n; q += 8) {
      const int t = ovf[q];
      const long rr = (long)cd[t].x;
      const float* __restrict__ rp = ui + rr * (long)T_;
      const int4 p = *(const int4*)&cd[((t >> 9) << 9) + j];
      const u32 pk = (u32)f2bf(rp[p.x] + __int_as_float(p.y)) |
                     ((u32)f2bf(rp[p.z] + __int_as_float(p.w)) << 16);
      *(u32*)&adj[(size_t)t * 512 + j] = pk;
    }
  }
}

// ---------------------------------------------------------------------------
// gemmT<LAYER>: SWAPPED-operand GEMM producing t[i][d] = sum_l adj[i][l]*x[l][d]
// via D[m=d][n=i] = mfma(A = x^T[d][l], B = adj[i][l]).
// Tile: 256 d x 128 i, BK=32, 16 k-steps, 8 waves (4 d-waves x 2 i-waves),
// wave tile 64d x 64i (2x2 of 32x32x16), acc = 64 VGPR.
// LAYER 0: x = enc f32 k-major -> reg-stage 8 dwordx2 + cvt_pk + swizzled
//          ds_write (single 16KB x-buffer, drained per step).
// LAYER 1: x = xb bf16 n-major [d][l] -> gload_lds, 3-buf.
// adj: gload_lds 3-buf. Stage-after-B2, counted vmcnt.
// Store: thread holds d-contiguous reg groups -> b64 coalesced stores (no relu).
// ---------------------------------------------------------------------------
template <int LAYER>
__global__ __launch_bounds__(512, LAYER == 0 ? 2 : 4)
void gemmT(const u16* __restrict__ adj, const void* __restrict__ Xv,
           u16* __restrict__ tb) {
  extern __shared__ u16 smem[];
  const int tid = threadIdx.x;
  const int lane = tid & 63;
  const int w = tid >> 6;
  const int wm = w >> 1;   // d-wave 0..3
  const int wn = w & 1;    // i-wave 0..1
  const int wg = blockIdx.x;
  const int mapped = (wg & 7) * 64 + (wg >> 3);  // grid 512, chunk 64
  const int batch = mapped >> 3;
  const int sub = mapped & 7;
  const int m0 = (sub >> 2) << 8;   // d-tile base
  const int n0i = (sub & 3) << 7;   // i-tile base
  const size_t PS = (size_t)512 * 512;
  const u16* __restrict__ adjB = adj + batch * PS;

  // adj staging: 8KB tile (128 i x 32 l), 1 chunk (16B)/thread
  const u16* gAdj;
  u32 ldAdj;
  {
    const int L = tid * 16;
    const int p = L >> 7;
    const int off = (L & 127) ^ ((p & 7) << 4);
    const int mr = p * 2 + (off >> 6);
    const int kb = off & 63;
    gAdj = adjB + (size_t)(n0i + mr) * 512 + (kb >> 1);
    ldAdj = (u32)(w * 512);  // elems within adj buf
  }
  // X staging state
  const u16* gX[2] = {nullptr, nullptr};
  u32 ldX[2] = {0, 0};
  unsigned long long encB = 0;
  u32 boff0 = 0;
  const int dp = tid & 127;
  const int lq = tid >> 7;
  u32x2 bs0[8], bs1[8];
  if (LAYER == 1) {
    const u16* __restrict__ xbB = (const u16*)Xv + batch * PS;
#pragma unroll
    for (int r = 0; r < 2; ++r) {
      const int c = r * 512 + tid;
      const int L = c * 16;
      const int p = L >> 7;
      const int off = (L & 127) ^ ((p & 7) << 4);
      const int mr = p * 2 + (off >> 6);
      const int kb = off & 63;
      gX[r] = xbB + (size_t)(m0 + mr) * 512 + (kb >> 1);
      ldX[r] = (u32)(r * 4096 + w * 512);
    }
  } else {
    encB = (unsigned long long)(uintptr_t)((const float*)Xv + batch * PS);
    boff0 = (u32)(((lq * 8) * 512 + m0 + dp * 2) * 4);
  }

#define ELOAD(t, S)                                                          \
  {                                                                          \
    const u32 ob = boff0 + (u32)(t) * 65536u;                                \
    _Pragma("unroll") for (int i = 0; i < 8; ++i)                            \
        asm volatile("global_load_dwordx2 %0, %1, %2"                        \
                     : "=v"(S[i])                                            \
                     : "v"(ob + (u32)i * 2048u), "s"(encB));                 \
  }

#define ECONV(S)                                                             \
  {                                                                          \
    u32 wrd0[4], wrd1[4];                                                    \
    _Pragma("unroll") for (int jj = 0; jj < 4; ++jj) {                       \
      asm("v_cvt_pk_bf16_f32 %0, %1, %2"                                     \
          : "=v"(wrd0[jj]) : "v"(S[2 * jj].x), "v"(S[2 * jj + 1].x));        \
      asm("v_cvt_pk_bf16_f32 %0, %1, %2"                                     \
          : "=v"(wrd1[jj]) : "v"(S[2 * jj].y), "v"(S[2 * jj + 1].y));        \
    }                                                                        \
    const u32 by0 = (u32)dp * 128u + ((((u32)lq * 16u)) ^ (((u32)dp & 7u) << 4)); \
    const u32 by1 = (u32)dp * 128u + ((64u | ((u32)lq * 16u)) ^ (((u32)dp & 7u) << 4)); \
    i32x4 v0, v1;                                                            \
    v0.x = (int)wrd0[0]; v0.y = (int)wrd0[1]; v0.z = (int)wrd0[2]; v0.w = (int)wrd0[3]; \
    v1.x = (int)wrd1[0]; v1.y = (int)wrd1[1]; v1.z = (int)wrd1[2]; v1.w = (int)wrd1[3]; \
    *(i32x4*)((char*)smem + by0) = v0;                                       \
    *(i32x4*)((char*)smem + by1) = v1;                                       \
  }

  const int col = lane & 31;
  const int h16 = (lane >> 5) * 16;
  // frag byte offsets within a tile
  u32 xOff[2][2], adjOff[2][2];
#pragma unroll
  for (int df = 0; df < 2; ++df)
#pragma unroll
    for (int kk = 0; kk < 2; ++kk)
      xOff[df][kk] = swz(wm * 64 + df * 32 + col, kk * 32 + h16);
#pragma unroll
  for (int f = 0; f < 2; ++f)
#pragma unroll
    for (int kk = 0; kk < 2; ++kk)
      adjOff[f][kk] = swz(wn * 64 + f * 32 + col, kk * 32 + h16);
  const u32 ldsBase = lds_off(smem);
  // LDS elem layout: LAYER0: X single @0 (8192), adj bufs @8192+q*4096
  //                  LAYER1: X bufs @q*8192, adj bufs @24576+q*4096
  const u32 XBQ[3] = {LAYER == 0 ? 0u : 0u, LAYER == 0 ? 0u : 16384u,
                      LAYER == 0 ? 0u : 32768u};            // bytes
  const u32 ABQ[3] = {LAYER == 0 ? 16384u : 49152u, LAYER == 0 ? 24576u : 57344u,
                      LAYER == 0 ? 32768u : 65536u};        // bytes

  f32x16 acc[2][2] = {};

  auto stageAdj = [&](int t) {
    gload_lds16(gAdj + t * 32, smem + (ABQ[t % 3] >> 1) + ldAdj);
  };
  auto stageX = [&](int t) {
#pragma unroll
    for (int r = 0; r < 2; ++r)
      gload_lds16(gX[r] + t * 32, smem + (XBQ[t % 3] >> 1) + ldX[r]);
  };

  if (LAYER == 0) {
    ELOAD(0, bs0); stageAdj(0); ELOAD(1, bs1); stageAdj(1);
  } else {
    stageX(0); stageAdj(0); stageX(1); stageAdj(1);
  }

#pragma unroll
  for (int t = 0; t < 16; ++t) {
    if (LAYER == 0) {
      if (t <= 14) asm volatile("s_waitcnt vmcnt(9)" ::: "memory");
      else         asm volatile("s_waitcnt vmcnt(0)" ::: "memory");
      __builtin_amdgcn_sched_barrier(0);
      if (t & 1) { ECONV(bs1); } else { ECONV(bs0); }
      if (t + 2 < 16) { if (t & 1) { ELOAD(t + 2, bs1); } else { ELOAD(t + 2, bs0); } }
      asm volatile("s_waitcnt lgkmcnt(0)" ::: "memory");  // drain my ds_writes
    } else {
      if (t <= 14) asm volatile("s_waitcnt vmcnt(3)" ::: "memory");
      else         asm volatile("s_waitcnt vmcnt(0)" ::: "memory");
      __builtin_amdgcn_sched_barrier(0);
    }
    __builtin_amdgcn_s_barrier();  // B1: tile-t staged by all waves
    asm volatile("" ::: "memory");

    const u32 xb_ = ldsBase + XBQ[t % 3];
    const u32 ab_ = ldsBase + ABQ[t % 3];
    i32x4 xr[2][2], ar[2][2];
#pragma unroll
    for (int df = 0; df < 2; ++df)
#pragma unroll
      for (int kk = 0; kk < 2; ++kk)
        asm volatile("ds_read_b128 %0, %1" : "=v"(xr[df][kk]) : "v"(xb_ + xOff[df][kk]));
#pragma unroll
    for (int f = 0; f < 2; ++f)
#pragma unroll
      for (int kk = 0; kk < 2; ++kk)
        asm volatile("ds_read_b128 %0, %1" : "=v"(ar[f][kk]) : "v"(ab_ + adjOff[f][kk]));
    asm volatile("s_waitcnt lgkmcnt(0)" ::: "memory");
    __builtin_amdgcn_sched_barrier(0);

    __builtin_amdgcn_s_setprio(1);
#pragma unroll
    for (int kk = 0; kk < 2; ++kk)
#pragma unroll
      for (int df = 0; df < 2; ++df)
#pragma unroll
        for (int f = 0; f < 2; ++f)
          acc[df][f] = __builtin_amdgcn_mfma_f32_32x32x16_bf16(
              __builtin_bit_cast(bf16x8, xr[df][kk]),
              __builtin_bit_cast(bf16x8, ar[f][kk]), acc[df][f], 0, 0, 0);
    __builtin_amdgcn_s_setprio(0);
    asm volatile("" ::: "memory");
    __builtin_amdgcn_s_barrier();  // B2: buf reads done
    __builtin_amdgcn_sched_barrier(0);
    if (t + 2 < 16) {
      if (LAYER == 1) stageX(t + 2);
      stageAdj(t + 2);
    }
  }
#undef ELOAD
#undef ECONV

  // store t[i][d]: i = lane-dim (fixed), d = reg-dim (4-consecutive groups)
  u16* tbB = tb + batch * PS;
#pragma unroll
  for (int df = 0; df < 2; ++df)
#pragma unroll
    for (int f = 0; f < 2; ++f) {
      const int i = n0i + wn * 64 + f * 32 + col;
      const int dbase = m0 + wm * 64 + df * 32 + 4 * (lane >> 5);
      const f32x16 v = acc[df][f];
#pragma unroll
      for (int g = 0; g < 4; ++g) {
        uint2 p;
        p.x = (u32)f2bf(v[g * 4 + 0]) | ((u32)f2bf(v[g * 4 + 1]) << 16);
        p.y = (u32)f2bf(v[g * 4 + 2]) | ((u32)f2bf(v[g * 4 + 3]) << 16);
        *(uint2*)&tbB[(size_t)i * 512 + dbase + 8 * g] = p;
      }
    }
}

// ---------------------------------------------------------------------------
// gemmW<MODE>: D[m=i][n=e] = t[i][d] @ W^T[e][d].  Tile 256 i x 128 e, BK=32,
// 8 waves (4 i-waves x 2 e-waves), wave 64x64, 3-buf gload_lds both operands.
// MODE 1: store relu -> xb[e][i] (b64, i-contiguous reg groups).
// MODE 2: relu + column partials P[batch][8][512] (slot = it*4 + wm).
// ---------------------------------------------------------------------------
template <int MODE>
__global__ __launch_bounds__(512, 4)
void gemmW(const u16* __restrict__ tbuf, const u16* __restrict__ wstL,
           u16* __restrict__ xbo, float* __restrict__ P) {
  extern __shared__ u16 smem[];
  const int tid = threadIdx.x;
  const int lane = tid & 63;
  const int w = tid >> 6;
  const int wm = w >> 1;   // i-wave 0..3
  const int wn = w & 1;    // e-wave 0..1
  const int wg = blockIdx.x;
  const int mapped = (wg & 7) * 64 + (wg >> 3);
  const int batch = mapped >> 3;
  const int sub = mapped & 7;
  const int it = sub >> 2;
  const int i0 = it << 8;
  const int e0 = (sub & 3) << 7;
  const size_t PS = (size_t)512 * 512;
  const u16* __restrict__ Ab = tbuf + batch * PS;

  // A staging: 16KB tile (256 i x 32 d), 2 chunks/thread
  const u16* gA[2];
  u32 ldA[2];
#pragma unroll
  for (int r = 0; r < 2; ++r) {
    const int c = r * 512 + tid;
    const int L = c * 16;
    const int p = L >> 7;
    const int off = (L & 127) ^ ((p & 7) << 4);
    const int mr = p * 2 + (off >> 6);
    const int kb = off & 63;
    gA[r] = Ab + (size_t)(i0 + mr) * 512 + (kb >> 1);
    ldA[r] = (u32)(r * 4096 + w * 512);
  }
  // B staging: 8KB tile (128 e x 32 d), 1 chunk/thread
  const u16* gB;
  u32 ldB;
  {
    const int L = tid * 16;
    const int p = L >> 7;
    const int off = (L & 127) ^ ((p & 7) << 4);
    const int mr = p * 2 + (off >> 6);
    const int kb = off & 63;
    gB = wstL + (size_t)(e0 + mr) * 512 + (kb >> 1);
    ldB = (u32)(w * 512);
  }

  const int col = lane & 31;
  const int h16 = (lane >> 5) * 16;
  u32 aOff[2][2], bOff[2][2];
#pragma unroll
  for (int mi = 0; mi < 2; ++mi)
#pragma unroll
    for (int kk = 0; kk < 2; ++kk)
      aOff[mi][kk] = swz(wm * 64 + mi * 32 + col, kk * 32 + h16);
#pragma unroll
  for (int ne = 0; ne < 2; ++ne)
#pragma unroll
    for (int kk = 0; kk < 2; ++kk)
      bOff[ne][kk] = swz(wn * 64 + ne * 32 + col, kk * 32 + h16);
  const u32 ldsBase = lds_off(smem);
  const u32 ABQ[3] = {0u, 16384u, 32768u};          // bytes
  const u32 BBQ[3] = {49152u, 57344u, 65536u};      // bytes

  f32x16 acc[2][2] = {};

  auto stage = [&](int t) {
#pragma unroll
    for (int r = 0; r < 2; ++r)
      gload_lds16(gA[r] + t * 32, smem + (ABQ[t % 3] >> 1) + ldA[r]);
    gload_lds16(gB + t * 32, smem + (BBQ[t % 3] >> 1) + ldB);
  };

  stage(0); stage(1);

#pragma unroll
  for (int t = 0; t < 16; ++t) {
    if (t <= 14) asm volatile("s_waitcnt vmcnt(3)" ::: "memory");
    else         asm volatile("s_waitcnt vmcnt(0)" ::: "memory");
    __builtin_amdgcn_sched_barrier(0);
    __builtin_amdgcn_s_barrier();  // B1
    asm volatile("" ::: "memory");

    const u32 ab_ = ldsBase + ABQ[t % 3];
    const u32 bb_ = ldsBase + BBQ[t % 3];
    i32x4 ar[2][2], br[2][2];
#pragma unroll
    for (int mi = 0; mi < 2; ++mi)
#pragma unroll
      for (int kk = 0; kk < 2; ++kk)
        asm volatile("ds_read_b128 %0, %1" : "=v"(ar[mi][kk]) : "v"(ab_ + aOff[mi][kk]));
#pragma unroll
    for (int ne = 0; ne < 2; ++ne)
#pragma unroll
      for (int kk = 0; kk < 2; ++kk)
        asm volatile("ds_read_b128 %0, %1" : "=v"(br[ne][kk]) : "v"(bb_ + bOff[ne][kk]));
    asm volatile("s_waitcnt lgkmcnt(0)" ::: "memory");
    __builtin_amdgcn_sched_barrier(0);

    __builtin_amdgcn_s_setprio(1);
#pragma unroll
    for (int kk = 0; kk < 2; ++kk)
#pragma unroll
      for (int mi = 0; mi < 2; ++mi)
#pragma unroll
        for (int ne = 0; ne < 2; ++ne)
          acc[mi][ne] = __builtin_amdgcn_mfma_f32_32x32x16_bf16(
              __builtin_bit_cast(bf16x8, ar[mi][kk]),
              __builtin_bit_cast(bf16x8, br[ne][kk]), acc[mi][ne], 0, 0, 0);
    __builtin_amdgcn_s_setprio(0);
    asm volatile("" ::: "memory");
    __builtin_amdgcn_s_barrier();  // B2
    __builtin_amdgcn_sched_barrier(0);
    if (t + 2 < 16) stage(t + 2);
  }

  if (MODE == 1) {
    // xb[e][i] = relu(D), i = reg-dim (contiguous) -> b64 stores
    u16* xbB = xbo + batch * PS;
#pragma unroll
    for (int mi = 0; mi < 2; ++mi)
#pragma unroll
      for (int ne = 0; ne < 2; ++ne) {
        const int e = e0 + wn * 64 + ne * 32 + col;
        const int ibase = i0 + wm * 64 + mi * 32 + 4 * (lane >> 5);
        const f32x16 v = acc[mi][ne];
#pragma unroll
        for (int g = 0; g < 4; ++g) {
          uint2 p;
          p.x = (u32)f2bf(fmaxf(v[g * 4 + 0], 0.f)) |
                ((u32)f2bf(fmaxf(v[g * 4 + 1], 0.f)) << 16);
          p.y = (u32)f2bf(fmaxf(v[g * 4 + 2], 0.f)) |
                ((u32)f2bf(fmaxf(v[g * 4 + 3], 0.f)) << 16);
          *(uint2*)&xbB[(size_t)e * 512 + ibase + 8 * g] = p;
        }
      }
  } else {
    // partial column sums over this wave's 64 i-rows
#pragma unroll
    for (int ne = 0; ne < 2; ++ne) {
      float s = 0.f;
#pragma unroll
      for (int mi = 0; mi < 2; ++mi) {
        const f32x16 v = acc[mi][ne];
#pragma unroll
        for (int r = 0; r < 16; ++r) s += fmaxf(v[r], 0.f);
      }
      s += __shfl_xor(s, 32);
      if (lane < 32) {
        const int e = e0 + wn * 64 + ne * 32 + lane;
        const int slot = it * 4 + wm;
        P[((size_t)batch * 8 + slot) * 512 + e] = s;
      }
    }
  }
}

// out[b,d] = (1/512) * sum_slot P[b][slot][d]
__global__ void reduce_mean(const float* __restrict__ P, float* __restrict__ out) {
  const int t = blockIdx.x * 256 + threadIdx.x;
  const int b = t >> 9, d = t & 511;
  float s = 0.f;
#pragma unroll
  for (int q = 0; q < 8; ++q) s += P[((size_t)b * 8 + q) * 512 + d];
  out[t] = s * (1.0f / 512.0f);
}

extern "C" void kernel_launch(void* const* d_in, const int* in_sizes, int n_in,
                              void* d_out, int out_size, void* d_ws, size_t ws_size,
                              hipStream_t stream) {
  const float* enc = (const float*)d_in[0];   // (64,512,512) f32
  const float* ui  = (const float*)d_in[1];   // (5000,5000) f32
  const float* Ws  = (const float*)d_in[2];   // (2,512,512) f32
  const int*   ev  = (const int*)d_in[3];     // (64,512) int
  float* out = (float*)d_out;                 // (64,512) f32

  char* ws = (char*)d_ws;
  const size_t SLAB = (size_t)64 * 512 * 512 * 2;  // 32 MiB
  u16* adj  = (u16*)(ws);
  u16* tbuf = (u16*)(ws + SLAB);
  u16* xb   = (u16*)(ws + 2 * SLAB);
  char* p = ws + 3 * SLAB;
  u16* wst  = (u16*)p;  p += (size_t)2 * 512 * 512 * 2;
  int2* cd  = (int2*)p; p += (size_t)32768 * 8;
  int* cnt  = (int*)p;  p += 5008 * 4;
  int* list = (int*)p;  p += (size_t)5000 * CAP * 4;
  int* ovf  = (int*)p;  p += (size_t)32768 * 4;
  float* P  = (float*)p;                               // [64][8][512] f32

  const size_t PS = (size_t)512 * 512;
  const size_t SM_T0 = 40960;   // X 16K + adj 3x8K
  const size_t SM_T1 = 73728;   // X 3x16K + adj 3x8K
  const size_t SM_W  = 73728;   // A 3x16K + B 3x8K
  (void)hipFuncSetAttribute(reinterpret_cast<const void*>(gemmT<0>),
                            hipFuncAttributeMaxDynamicSharedMemorySize, (int)SM_T0);
  (void)hipFuncSetAttribute(reinterpret_cast<const void*>(gemmT<1>),
                            hipFuncAttributeMaxDynamicSharedMemorySize, (int)SM_T1);
  (void)hipFuncSetAttribute(reinterpret_cast<const void*>(gemmW<1>),
                            hipFuncAttributeMaxDynamicSharedMemorySize, (int)SM_W);
  (void)hipFuncSetAttribute(reinterpret_cast<const void*>(gemmW<2>),
                            hipFuncAttributeMaxDynamicSharedMemorySize, (int)SM_W);

  prep_k<<<dim3(16, 16, 2), dim3(32, 8), 0, stream>>>(Ws, wst, cnt);
  fill_k<<<128, 256, 0, stream>>>(ev, ui, cd, cnt, list, ovf);
  grow_gather<<<5000, 256, 0, stream>>>(ui, cd, cnt, list, ovf, adj);
  // layer 0
  gemmT<0><<<512, 512, SM_T0, stream>>>(adj, enc, tbuf);
  gemmW<1><<<512, 512, SM_W, stream>>>(tbuf, wst, xb, nullptr);
  // layer 1
  gemmT<1><<<512, 512, SM_T1, stream>>>(adj, xb, tbuf);
  gemmW<2><<<512, 512, SM_W, stream>>>(tbuf, wst + PS, nullptr, P);
  reduce_mean<<<128, 256, 0, stream>>>(P, out);
}

// Round 8
// 142.606 us; speedup vs baseline: 1.2115x; 1.2115x over previous
//
#include <hip/hip_runtime.h>

typedef unsigned short u16;
typedef unsigned int u32;
typedef __bf16 bf16x8 __attribute__((ext_vector_type(8)));
typedef float f32x4 __attribute__((ext_vector_type(4)));
typedef int i32x4 __attribute__((ext_vector_type(4)));
typedef u32 u32x2 __attribute__((ext_vector_type(2)));
typedef u32 u32x4 __attribute__((ext_vector_type(4)));

#define T_ 5000
#define CAP 96  // bucket capacity; ovf path guarantees correctness on overflow

__device__ __forceinline__ u16 f2bf(float f) {
  u32 u = __float_as_uint(f);
  u += 0x7fffu + ((u >> 16) & 1u);
  return (u16)(u >> 16);
}

__device__ __forceinline__ void gload_lds16(const u16* g, u16* l) {
  __builtin_amdgcn_global_load_lds(
      (__attribute__((address_space(1))) void*)(u16*)g,
      (__attribute__((address_space(3))) void*)l, 16, 0, 0);
}

__device__ __forceinline__ u32 lds_off(const void* p) {
  return (u32)(uintptr_t)(__attribute__((address_space(3))) const void*)p;
}

// LDS tile swizzle (involution): tile byte (row, kb in [0,64)) ->
//   (row>>1)*128 + ((((row&1)<<6)|kb) ^ (((row>>1)&7)<<4))
__device__ __forceinline__ u32 swz(int row, int kb) {
  return (u32)((row >> 1) * 128 +
               ((((row & 1) << 6) | kb) ^ (((row >> 1) & 7) << 4)));
}

// Ws transpose (f32 [2][512][512] -> bf16 transposed) + zero bucket counters
__global__ void prep_k(const float* __restrict__ src, u16* __restrict__ dst,
                       int* __restrict__ cnt) {
  __shared__ float tile[32][33];
  const int tx = threadIdx.x, ty = threadIdx.y;
  const int a0 = blockIdx.x * 32;
  const int b0 = blockIdx.y * 32;
  const size_t zoff = (size_t)blockIdx.z * (512 * 512);
  const float* s = src + zoff;
  u16* d = dst + zoff;
#pragma unroll
  for (int r = 0; r < 4; ++r)
    tile[ty + r * 8][tx] = s[(size_t)(a0 + ty + r * 8) * 512 + b0 + tx];
  const int gid = ((blockIdx.z * 16 + blockIdx.y) * 16 + blockIdx.x) * 256 + ty * 32 + tx;
  if (gid < 5008) cnt[gid] = 0;
  __syncthreads();
#pragma unroll
  for (int r = 0; r < 4; ++r)
    d[(size_t)(b0 + ty + r * 8) * 512 + a0 + tx] = f2bf(tile[tx][ty + r * 8]);
}

// cd[t] = {col, bits(diag)}; bucket instance t into list[row]
__global__ void fill_k(const int* __restrict__ ev, const float* __restrict__ ui,
                       int2* __restrict__ cd, int* __restrict__ cnt,
                       int* __restrict__ list, int* __restrict__ ovf) {
  const int t = blockIdx.x * 256 + threadIdx.x;  // 0..32767
  const int r = ev[t] - 1;
  int2 v;
  v.x = r;
  v.y = __float_as_int(ui[(size_t)r * (T_ + 1)]);
  cd[t] = v;
  const int pos = atomicAdd(&cnt[r], 1);
  if (pos < CAP) list[r * CAP + pos] = t;
  else { const int o = atomicAdd(&cnt[5000], 1); ovf[o] = t; }
}

// one block per distinct ui row: stage row + instance list in LDS, serve 4-way.
// blocks 0..7 additionally serve the (expected-empty) overflow list.
__global__ __launch_bounds__(256)
void grow_gather(const float* __restrict__ ui, const int2* __restrict__ cd,
                 const int* __restrict__ cnt, const int* __restrict__ list,
                 const int* __restrict__ ovf, u16* __restrict__ adj) {
  __shared__ float row[5000];
  __shared__ int lst[CAP];
  const int r = blockIdx.x;
  int c = cnt[r];
  if (c > CAP) c = CAP;
  const int j = threadIdx.x * 2;
  if (c > 0) {
    const float* __restrict__ src = ui + (size_t)r * T_;
    for (int t = threadIdx.x; t < 1250; t += 256)
      *(float4*)&row[t * 4] = *(const float4*)&src[t * 4];
    if (threadIdx.x < c) lst[threadIdx.x] = list[r * CAP + threadIdx.x];
    __syncthreads();
    int q = 0;
    for (; q + 4 <= c; q += 4) {
      const int t0 = lst[q], t1 = lst[q + 1], t2 = lst[q + 2], t3 = lst[q + 3];
      const int4 p0 = *(const int4*)&cd[((t0 >> 9) << 9) + j];
      const int4 p1 = *(const int4*)&cd[((t1 >> 9) << 9) + j];
      const int4 p2 = *(const int4*)&cd[((t2 >> 9) << 9) + j];
      const int4 p3 = *(const int4*)&cd[((t3 >> 9) << 9) + j];
      const u32 k0 = (u32)f2bf(row[p0.x] + __int_as_float(p0.y)) |
                     ((u32)f2bf(row[p0.z] + __int_as_float(p0.w)) << 16);
      const u32 k1 = (u32)f2bf(row[p1.x] + __int_as_float(p1.y)) |
                     ((u32)f2bf(row[p1.z] + __int_as_float(p1.w)) << 16);
      const u32 k2 = (u32)f2bf(row[p2.x] + __int_as_float(p2.y)) |
                     ((u32)f2bf(row[p2.z] + __int_as_float(p2.w)) << 16);
      const u32 k3 = (u32)f2bf(row[p3.x] + __int_as_float(p3.y)) |
                     ((u32)f2bf(row[p3.z] + __int_as_float(p3.w)) << 16);
      *(u32*)&adj[(size_t)t0 * 512 + j] = k0;
      *(u32*)&adj[(size_t)t1 * 512 + j] = k1;
      *(u32*)&adj[(size_t)t2 * 512 + j] = k2;
      *(u32*)&adj[(size_t)t3 * 512 + j] = k3;
    }
    for (; q < c; ++q) {
      const int t0 = lst[q];
      const int4 p0 = *(const int4*)&cd[((t0 >> 9) << 9) + j];
      const u32 k0 = (u32)f2bf(row[p0.x] + __int_as_float(p0.y)) |
                     ((u32)f2bf(row[p0.z] + __int_as_float(p0.w)) << 16);
      *(u32*)&adj[(size_t)t0 * 512 + j] = k0;
    }
  }
  if (r < 8) {
    const int n = cnt[5000];
    for (int q = r; q < n; q += 8) {
      const int t = ovf[q];
      const long rr = (long)cd[t].x;
      const float* __restrict__ rp = ui + rr * (long)T_;
      const int4 p = *(const int4*)&cd[((t >> 9) << 9) + j];
      const u32 pk = (u32)f2bf(rp[p.x] + __int_as_float(p.y)) |
                     ((u32)f2bf(rp[p.z] + __int_as_float(p.w)) << 16);
      *(u32*)&adj[(size_t)t * 512 + j] = pk;
    }
  }
}

// ---------------------------------------------------------------------------
// 256x256-tile GEMM (R5 engine), BK=32, 8 waves (2x4), wave tile 128x64,
// 16x16x32 MFMA, 4 LDS bufs/region, prefetch depth 3, counted vmcnt,
// raw barriers, asm ds_read_b128, XOR swizzle, chunked XCD swizzle.
// region0 @0 (4x16KB, gload_lds), region1 @64K (BSRC0: 4x16KB gload_lds;
// BSRC1: single 16KB, reg-staged f32 + cvt_pk + swizzled ds_write).
// MODE 1: C = relu(A@B) stored transposed Cb[n][m] (b64).   [G2]
// MODE 2: relu + column partials P[b][slot][d].              [G4]
// MODE 3: SWAPPED roles: 8-frag set from region1 (m=d), 4-frag from region0
//         (n=i), D[m=d][n=i] -> store t[i][d] b64 (no relu). [G1,G3]
// Staging row bases: region0 = (MODE3 ? n0 : m0), region1 = (MODE3 ? m0 : n0).
// ---------------------------------------------------------------------------
template <int MODE, int BSRC>
__global__ __launch_bounds__(512, 2)
void gemm256(const u16* __restrict__ A, const void* __restrict__ Bv,
             u16* __restrict__ C, size_t strideA, size_t strideB, size_t strideC,
             float* __restrict__ P) {
  extern __shared__ u16 smem[];
  const int tid = threadIdx.x;
  const int lane = tid & 63;
  const int w = tid >> 6;
  const int wm = w >> 2, wn = w & 3;
  const int chunk = gridDim.x >> 3;
  const int wg = blockIdx.x;
  const int mapped = (wg & 7) * chunk + (wg >> 3);
  const int batch = mapped >> 2;
  const int tm = (mapped >> 1) & 1, tn = mapped & 1;
  const int m0 = tm << 8, n0 = tn << 8;
  const int r0base = (MODE == 3) ? n0 : m0;
  const int r1base = (MODE == 3) ? m0 : n0;
  const u16* __restrict__ Ab = A + (size_t)batch * strideA;

  // region0 staging: 2 chunks (16B)/thread, inverse-swizzled source
  const u16* gA[2];
  u32 ldA[2];
#pragma unroll
  for (int r = 0; r < 2; ++r) {
    const int c = r * 512 + tid;
    const int L = c * 16;
    const int pp = L >> 7;
    const int off = (L & 127) ^ ((pp & 7) << 4);
    const int m = pp * 2 + (off >> 6);
    const int kb = off & 63;
    gA[r] = Ab + (size_t)(r0base + m) * 512 + (kb >> 1);
    ldA[r] = (u32)((r * 512 + w * 64) * 8);  // u16 elems; +lane*16B by HW
  }

  // BSRC0 region1 staging
  const u16* gB[2] = {nullptr, nullptr};
  u32 ldB[2] = {0, 0};
  if (BSRC == 0) {
    const u16* __restrict__ Bb = (const u16*)Bv + (size_t)batch * strideB;
#pragma unroll
    for (int r = 0; r < 2; ++r) {
      const int c = r * 512 + tid;
      const int L = c * 16;
      const int pp = L >> 7;
      const int off = (L & 127) ^ ((pp & 7) << 4);
      const int m = pp * 2 + (off >> 6);
      const int kb = off & 63;
      gB[r] = Bb + (size_t)(r1base + m) * 512 + (kb >> 1);
      ldB[r] = (u32)(32768 + (r * 512 + w * 64) * 8);
    }
  }

  // BSRC1 region1 staging: 8 k x 2 cols per thread (f32 k-major source)
  const int dp = tid & 127;
  const int lq = tid >> 7;
  unsigned long long encB = 0;
  u32 boff0 = 0;
  u32x2 bs0[8], bs1[8];
  if (BSRC == 1) {
    encB = (unsigned long long)(uintptr_t)((const float*)Bv + (size_t)batch * strideB);
    boff0 = (u32)(((lq * 8) * 512 + r1base + dp * 2) * 4);
  }

#define BLOAD(t, S)                                                          \
  {                                                                          \
    const u32 ob = boff0 + (u32)(t) * 65536u;                                \
    _Pragma("unroll") for (int i = 0; i < 8; ++i)                            \
        asm volatile("global_load_dwordx2 %0, %1, %2"                        \
                     : "=v"(S[i])                                            \
                     : "v"(ob + (u32)i * 2048u), "s"(encB));                 \
  }

#define CONVERT_B(S)                                                         \
  {                                                                          \
    u32 wrd0[4], wrd1[4];                                                    \
    _Pragma("unroll") for (int jj = 0; jj < 4; ++jj) {                       \
      asm("v_cvt_pk_bf16_f32 %0, %1, %2"                                     \
          : "=v"(wrd0[jj]) : "v"(S[2 * jj].x), "v"(S[2 * jj + 1].x));        \
      asm("v_cvt_pk_bf16_f32 %0, %1, %2"                                     \
          : "=v"(wrd1[jj]) : "v"(S[2 * jj].y), "v"(S[2 * jj + 1].y));        \
    }                                                                        \
    const u32 by0 = (u32)dp * 128u + ((((u32)lq * 16u)) ^ (((u32)dp & 7u) << 4)); \
    const u32 by1 = (u32)dp * 128u + ((64u | ((u32)lq * 16u)) ^ (((u32)dp & 7u) << 4)); \
    u32x4 v0, v1;                                                            \
    v0.x = wrd0[0]; v0.y = wrd0[1]; v0.z = wrd0[2]; v0.w = wrd0[3];          \
    v1.x = wrd1[0]; v1.y = wrd1[1]; v1.z = wrd1[2]; v1.w = wrd1[3];          \
    *(u32x4*)((char*)smem + 65536 + by0) = v0;                               \
    *(u32x4*)((char*)smem + 65536 + by1) = v1;                               \
  }

  // frag LDS byte offsets (region-relative)
  const int lr = lane & 15;
  const int kbB = (lane >> 4) << 4;  // bytes
  u32 fOff8[8], fOff4[4];
#pragma unroll
  for (int m = 0; m < 8; ++m) fOff8[m] = swz(wm * 128 + m * 16 + lr, kbB);
#pragma unroll
  for (int n = 0; n < 4; ++n) fOff4[n] = swz(wn * 64 + n * 16 + lr, kbB);
  const u32 ldsBase = lds_off(smem);

  f32x4 acc[8][4] = {};

  auto stageA = [&](int t) {
    const u32 bo = (u32)(t & 3) * 8192;
#pragma unroll
    for (int r = 0; r < 2; ++r) gload_lds16(gA[r] + t * 32, smem + bo + ldA[r]);
  };
  auto stageB0 = [&](int t) {
    const u32 bo = (u32)(t & 3) * 8192;
#pragma unroll
    for (int r = 0; r < 2; ++r) gload_lds16(gB[r] + t * 32, smem + bo + ldB[r]);
  };

  if (BSRC == 0) {
    stageA(0); stageB0(0); stageA(1); stageB0(1); stageA(2); stageB0(2);
  } else {
    stageA(0); stageA(1); stageA(2);
    BLOAD(0, bs0); BLOAD(1, bs1);
  }

#pragma unroll
  for (int t = 0; t < 16; ++t) {
    if (BSRC == 0) {
      if (t <= 13)      asm volatile("s_waitcnt vmcnt(8)" ::: "memory");
      else if (t == 14) asm volatile("s_waitcnt vmcnt(4)" ::: "memory");
      else              asm volatile("s_waitcnt vmcnt(0)" ::: "memory");
      __builtin_amdgcn_sched_barrier(0);
      if (t + 3 < 16) { stageA(t + 3); stageB0(t + 3); }
      asm volatile("" ::: "memory");
      __builtin_amdgcn_s_barrier();  // B1
      asm volatile("" ::: "memory");
    } else {
      if (t == 0)              asm volatile("s_waitcnt vmcnt(8)" ::: "memory");
      else if (t <= 13)        asm volatile("s_waitcnt vmcnt(10)" ::: "memory");
      else if (t == 14)        asm volatile("s_waitcnt vmcnt(8)" ::: "memory");
      else                     asm volatile("s_waitcnt vmcnt(0)" ::: "memory");
      __builtin_amdgcn_sched_barrier(0);
      if (t & 1) { CONVERT_B(bs1); } else { CONVERT_B(bs0); }
      if (t + 3 < 16) stageA(t + 3);
      if (t + 2 < 16) { if (t & 1) { BLOAD(t + 2, bs1); } else { BLOAD(t + 2, bs0); } }
      asm volatile("s_waitcnt lgkmcnt(0)" ::: "memory");  // drain my ds_writes
      __builtin_amdgcn_s_barrier();  // B1
      asm volatile("" ::: "memory");
    }

    const u32 c0 = ldsBase + (u32)(t & 3) * 16384;
    const u32 c1 = ldsBase + 65536u + (BSRC == 0 ? (u32)(t & 3) * 16384 : 0u);
    const u32 base8 = (MODE == 3) ? c1 : c0;
    const u32 base4 = (MODE == 3) ? c0 : c1;
    i32x4 araw[8], braw[4];
#pragma unroll
    for (int m = 0; m < 8; ++m)
      asm volatile("ds_read_b128 %0, %1" : "=v"(araw[m]) : "v"(base8 + fOff8[m]));
#pragma unroll
    for (int n = 0; n < 4; ++n)
      asm volatile("ds_read_b128 %0, %1" : "=v"(braw[n]) : "v"(base4 + fOff4[n]));
    asm volatile("s_waitcnt lgkmcnt(0)" ::: "memory");
    __builtin_amdgcn_sched_barrier(0);

    __builtin_amdgcn_s_setprio(1);
#pragma unroll
    for (int m = 0; m < 8; ++m)
#pragma unroll
      for (int n = 0; n < 4; ++n)
        acc[m][n] = __builtin_amdgcn_mfma_f32_16x16x32_bf16(
            __builtin_bit_cast(bf16x8, araw[m]),
            __builtin_bit_cast(bf16x8, braw[n]), acc[m][n], 0, 0, 0);
    __builtin_amdgcn_s_setprio(0);
    asm volatile("" ::: "memory");
    __builtin_amdgcn_s_barrier();  // B2
    __builtin_amdgcn_sched_barrier(0);
  }
#undef BLOAD
#undef CONVERT_B

  u16* Cb = C + (size_t)batch * strideC;
  // C/D frag mapping: col = lane&15, row = (lane>>4)*4 + j
  if (MODE == 1) {
    // xb[e][i] = relu(D[m=i][n=e]); 4 consecutive i in regs -> b64
#pragma unroll
    for (int m = 0; m < 8; ++m) {
      const int i = m0 + wm * 128 + m * 16 + (lane >> 4) * 4;
#pragma unroll
      for (int n = 0; n < 4; ++n) {
        const int d = n0 + wn * 64 + n * 16 + (lane & 15);
        const f32x4 v = acc[m][n];
        uint2 p;
        p.x = (u32)f2bf(fmaxf(v[0], 0.f)) | ((u32)f2bf(fmaxf(v[1], 0.f)) << 16);
        p.y = (u32)f2bf(fmaxf(v[2], 0.f)) | ((u32)f2bf(fmaxf(v[3], 0.f)) << 16);
        *(uint2*)&Cb[(size_t)d * 512 + i] = p;
      }
    }
  } else if (MODE == 2) {
    const int slot = tm * 2 + wm;
#pragma unroll
    for (int n = 0; n < 4; ++n) {
      float s = 0.f;
#pragma unroll
      for (int m = 0; m < 8; ++m) {
        const f32x4 v = acc[m][n];
#pragma unroll
        for (int j = 0; j < 4; ++j) s += fmaxf(v[j], 0.f);
      }
      s += __shfl_xor(s, 16);
      s += __shfl_xor(s, 32);
      if ((lane >> 4) == 0) {
        const int d = n0 + wn * 64 + n * 16 + lane;
        P[((size_t)batch * 4 + slot) * 512 + d] = s;
      }
    }
  } else {
    // MODE 3: D[m=d][n=i] -> t[i][d], 4 consecutive d in regs -> b64, no relu
#pragma unroll
    for (int m = 0; m < 8; ++m) {
      const int dd = m0 + wm * 128 + m * 16 + (lane >> 4) * 4;
#pragma unroll
      for (int n = 0; n < 4; ++n) {
        const int ii = n0 + wn * 64 + n * 16 + (lane & 15);
        const f32x4 v = acc[m][n];
        uint2 p;
        p.x = (u32)f2bf(v[0]) | ((u32)f2bf(v[1]) << 16);
        p.y = (u32)f2bf(v[2]) | ((u32)f2bf(v[3]) << 16);
        *(uint2*)&Cb[(size_t)ii * 512 + dd] = p;
      }
    }
  }
}

// out[b,d] = (1/512) * sum_slot P[b][slot][d]
__global__ void reduce_mean(const float* __restrict__ P, float* __restrict__ out) {
  const int t = blockIdx.x * 256 + threadIdx.x;
  const int b = t >> 9, d = t & 511;
  float s = 0.f;
#pragma unroll
  for (int q = 0; q < 4; ++q) s += P[((size_t)b * 4 + q) * 512 + d];
  out[t] = s * (1.0f / 512.0f);
}

extern "C" void kernel_launch(void* const* d_in, const int* in_sizes, int n_in,
                              void* d_out, int out_size, void* d_ws, size_t ws_size,
                              hipStream_t stream) {
  const float* enc = (const float*)d_in[0];   // (64,512,512) f32
  const float* ui  = (const float*)d_in[1];   // (5000,5000) f32
  const float* Ws  = (const float*)d_in[2];   // (2,512,512) f32
  const int*   ev  = (const int*)d_in[3];     // (64,512) int
  float* out = (float*)d_out;                 // (64,512) f32

  char* ws = (char*)d_ws;
  const size_t SLAB = (size_t)64 * 512 * 512 * 2;  // 32 MiB
  u16* adj  = (u16*)(ws);
  u16* tbuf = (u16*)(ws + SLAB);
  u16* xb   = (u16*)(ws + 2 * SLAB);
  char* p = ws + 3 * SLAB;
  u16* wst  = (u16*)p;  p += (size_t)2 * 512 * 512 * 2;
  int2* cd  = (int2*)p; p += (size_t)32768 * 8;
  int* cnt  = (int*)p;  p += 5008 * 4;
  int* list = (int*)p;  p += (size_t)5000 * CAP * 4;
  int* ovf  = (int*)p;  p += (size_t)32768 * 4;
  float* P  = (float*)p;                               // [64][4][512] f32

  const size_t PS = (size_t)512 * 512;
  const size_t SMEM0 = 131072;  // BSRC0: region0 4x16K + region1 4x16K
  const size_t SMEM1 = 81920;   // BSRC1: region0 4x16K + region1 1x16K
  (void)hipFuncSetAttribute(reinterpret_cast<const void*>(gemm256<3, 1>),
                            hipFuncAttributeMaxDynamicSharedMemorySize, (int)SMEM1);
  (void)hipFuncSetAttribute(reinterpret_cast<const void*>(gemm256<1, 0>),
                            hipFuncAttributeMaxDynamicSharedMemorySize, (int)SMEM0);
  (void)hipFuncSetAttribute(reinterpret_cast<const void*>(gemm256<3, 0>),
                            hipFuncAttributeMaxDynamicSharedMemorySize, (int)SMEM0);
  (void)hipFuncSetAttribute(reinterpret_cast<const void*>(gemm256<2, 0>),
                            hipFuncAttributeMaxDynamicSharedMemorySize, (int)SMEM0);

  prep_k<<<dim3(16, 16, 2), dim3(32, 8), 0, stream>>>(Ws, wst, cnt);
  fill_k<<<128, 256, 0, stream>>>(ev, ui, cd, cnt, list, ovf);
  grow_gather<<<5000, 256, 0, stream>>>(ui, cd, cnt, list, ovf, adj);
  // layer 0: t = adj @ enc (f32 k-major region1, fused cast; swapped store)
  gemm256<3, 1><<<256, 512, SMEM1, stream>>>(adj, enc, tbuf, PS, PS, PS, nullptr);
  gemm256<1, 0><<<256, 512, SMEM0, stream>>>(tbuf, wst, xb, PS, 0, PS, nullptr);
  // layer 1 (+ fused mean partials)
  gemm256<3, 0><<<256, 512, SMEM0, stream>>>(adj, xb, tbuf, PS, PS, PS, nullptr);
  gemm256<2, 0><<<256, 512, SMEM0, stream>>>(tbuf, wst + PS, nullptr, PS, 0, 0, P);
  reduce_mean<<<128, 256, 0, stream>>>(P, out);
}